// Round 4
// baseline (2001.269 us; speedup 1.0000x reference)
//
#include <hip/hip_runtime.h>
#include <math.h>

// ConvGRU fused per-timestep kernel, v3: 4 pixels/thread x 1 output channel.
// x: (4,16,64,64,64) f32, Wx: (96,16,3,3), bx: (96), Wh: (96,32,3,3).
// r-gate is dead in the reference: only gate rows [0,32) (z) and [64,96) (n).
// Block = 16x64 pixel tile, one output channel; inputs staged in LDS in 6
// chunks of 8 channels. Each thread: 4 adjacent rows, so 18 weight floats
// amortize over 72 FMAs per cin (4x better than R2 -> fewer lgkm drains).
// h ping-pongs d_out <-> d_ws; t=63 writes d_out.

#define LW 72
#define DOFF 4
#define ROWS 18                      // 16 tile rows + 2 halo
#define LDS_FLOATS (8 * ROWS * LW)   // 10368 floats = 41.5 KB

__global__ __launch_bounds__(256, 2) void convgru_step(
    const float* __restrict__ x, const float* __restrict__ Wx,
    const float* __restrict__ bx, const float* __restrict__ Wh,
    const float* __restrict__ hsrc, float* __restrict__ hdst, int t)
{
    __shared__ float lds[LDS_FLOATS];
    const int tx   = threadIdx.x;
    const int y0   = blockIdx.x * 16;      // tile rows y0..y0+15
    const int c    = blockIdx.y;           // output channel (uniform)
    const int b    = blockIdx.z;
    const int quad = tx >> 6;              // 0..3: rows quad*4..quad*4+3
    const int col  = tx & 63;

    // prefetch h_prev for the 4 output pixels (coalesced, hidden latency)
    float hprev[4];
    #pragma unroll
    for (int j = 0; j < 4; ++j)
        hprev[j] = hsrc[(size_t)(b * 32 + c) * 4096 + (y0 + quad * 4 + j) * 64 + col];

    // zero halo columns once (144 rows x 2 cols = 288 entries; staging never
    // writes cols DOFF-1 / DOFF+64)
    #pragma unroll
    for (int i = 0; i < 2; ++i) {
        int task = i * 256 + tx;
        if (task < 288)
            lds[(task >> 1) * LW + ((task & 1) ? (DOFF + 64) : (DOFF - 1))] = 0.0f;
    }

    float acc[8];                          // [px j][gate z=0,n=1]
    #pragma unroll
    for (int j = 0; j < 4; ++j) {
        acc[2 * j]     = bx[c];
        acc[2 * j + 1] = bx[64 + c];
    }

    for (int chunk = 0; chunk < 6; ++chunk) {
        const float* src;
        const float* wz0;
        const float* wn0;
        size_t chanStride;
        if (chunk < 2) {
            const int ch0 = chunk * 8;
            src = x + ((size_t)(b * 16 + ch0) * 64 + t) * 4096;
            chanStride = (size_t)64 * 4096;
            wz0 = Wx + (size_t)(c * 16 + ch0) * 9;
            wn0 = Wx + (size_t)((64 + c) * 16 + ch0) * 9;
        } else {
            const int hc0 = (chunk - 2) * 8;
            src = hsrc + (size_t)(b * 32 + hc0) * 4096;
            chanStride = 4096;
            wz0 = Wh + (size_t)(c * 32 + hc0) * 9;
            wn0 = Wh + (size_t)((64 + c) * 32 + hc0) * 9;
        }

        __syncthreads();  // previous compute (or halo zeroing) done before restage
        // stage 8 channels x 18 halo rows x 64 cols as float4 (2304 tasks)
        #pragma unroll
        for (int i = 0; i < 9; ++i) {
            int task = i * 256 + tx;
            int f4   = task & 15;          // float4 index within row
            int rowg = task >> 4;          // 0..143 = ch*18 + r
            int ch   = rowg / 18;
            int r    = rowg - ch * 18;
            int yy   = y0 - 1 + r;
            float4 v = make_float4(0.f, 0.f, 0.f, 0.f);
            if ((unsigned)yy < 64u)
                v = *(const float4*)(src + ch * chanStride + yy * 64 + f4 * 4);
            *(float4*)&lds[rowg * LW + DOFF + f4 * 4] = v;   // 16B-aligned
        }
        __syncthreads();

        #pragma unroll
        for (int cin = 0; cin < 8; ++cin) {
            // 6-row x 3-col neighborhood covering pixels rows quad*4..quad*4+3
            const float* lb = &lds[(cin * ROWS + quad * 4) * LW + DOFF + col - 1];
            float v[6][3];
            #pragma unroll
            for (int rr = 0; rr < 6; ++rr) {
                v[rr][0] = lb[rr * LW];
                v[rr][1] = lb[rr * LW + 1];
                v[rr][2] = lb[rr * LW + 2];
            }
            const float* wz = wz0 + cin * 9;
            const float* wn = wn0 + cin * 9;
            float wzr[9], wnr[9];
            #pragma unroll
            for (int k = 0; k < 9; ++k) { wzr[k] = wz[k]; wnr[k] = wn[k]; }
            #pragma unroll
            for (int j = 0; j < 4; ++j) {
                #pragma unroll
                for (int kr = 0; kr < 3; ++kr) {
                    #pragma unroll
                    for (int kc = 0; kc < 3; ++kc) {
                        acc[2 * j]     = fmaf(v[j + kr][kc], wzr[kr * 3 + kc], acc[2 * j]);
                        acc[2 * j + 1] = fmaf(v[j + kr][kc], wnr[kr * 3 + kc], acc[2 * j + 1]);
                    }
                }
            }
        }
    }

    #pragma unroll
    for (int j = 0; j < 4; ++j) {
        const int p = (y0 + quad * 4 + j) * 64 + col;
        float z = 1.0f / (1.0f + __expf(-acc[2 * j]));
        float e = __expf(2.0f * acc[2 * j + 1]);
        float n = 1.0f - 2.0f / (e + 1.0f);          // tanh, overflow-safe
        hdst[(size_t)(b * 32 + c) * 4096 + p] = (1.0f - z) * hprev[j] + z * n;
    }
}

extern "C" void kernel_launch(void* const* d_in, const int* in_sizes, int n_in,
                              void* d_out, int out_size, void* d_ws, size_t ws_size,
                              hipStream_t stream) {
    const float* x  = (const float*)d_in[0];
    const float* Wx = (const float*)d_in[1];
    const float* bx = (const float*)d_in[2];
    const float* Wh = (const float*)d_in[3];
    float* out = (float*)d_out;
    float* ws  = (float*)d_ws;

    // h0 = zeros in d_out (even t: read out -> write ws; odd t: read ws -> write out;
    // t=63 odd => final h lands in d_out).
    hipMemsetAsync(d_out, 0, (size_t)524288 * sizeof(float), stream);

    dim3 grid(4, 32, 4), block(256);
    for (int t = 0; t < 64; ++t) {
        const float* src = (t & 1) ? ws : out;
        float*       dst = (t & 1) ? out : ws;
        hipLaunchKernelGGL(convgru_step, grid, block, 0, stream,
                           x, Wx, bx, Wh, src, dst, t);
    }
}